// Round 9
// baseline (334.642 us; speedup 1.0000x reference)
//
#include <hip/hip_runtime.h>
#include <hip/hip_fp16.h>

#define N_NODES 50000
#define E_EDGES 800000
#define H_HEADS 4
#define IN_DIM 256
#define HF 128   // H*F
#define NEG_SLOPE 0.2f
#define MAXD 64                  // max in-degree slots (Poisson(16): P(>64) ~ 1e-20)
#define NPB 16                   // nodes per gather block (4 waves x 4 quarters)
#define PROJ_BLOCKS 1563         // ceil(50000/32)
#define SCAT_BLOCKS 3125         // 800000/256
#define TOT_BLOCKS (PROJ_BLOCKS + SCAT_BLOCKS)   // 4688; b%3==0 -> proj (1563), else scatter (3125)

// ---------------- K1: fused node projection + payload scatter (interleaved blocks)
__global__ __launch_bounds__(256) void k_proj_scatter(
    const float* __restrict__ feat,    // [N,256] f32
    const float* __restrict__ W_fc,    // [256,128] f32
    const float* __restrict__ attn_l,  // [128] f32
    const float* __restrict__ attn_r,  // [128] f32
    const int* __restrict__ src, const int* __restrict__ dst,
    const float* __restrict__ edge_fea,  // [E,5] f32
    __half2* __restrict__ feat_src,    // [N,64] half2
    float* __restrict__ el,            // [N,4] f32
    float* __restrict__ er,            // [N,4] f32
    int* __restrict__ cnt,             // [N] (zeroed)
    uint4* __restrict__ slots)         // [N,MAXD] payload {src, ef fp16 x5}
{
    int b = blockIdx.x;
    if (b % 3 != 0) {
        // ---- scatter part: histogram + 16B payload store
        int sb = b - b / 3 - 1;            // 0..3124
        int e  = sb * 256 + threadIdx.x;
        if (e < E_EDGES) {
            int d = dst[e];
            int pos = atomicAdd(&cnt[d], 1);
            if (pos < MAXD) {
                int s = src[e];
                const float* ep = edge_fea + (size_t)e * 5;
                __half2 p01 = __floats2half2_rn(ep[0], ep[1]);
                __half2 p23 = __floats2half2_rn(ep[2], ep[3]);
                __half2 p4x = __floats2half2_rn(ep[4], 0.f);
                uint4 pk = make_uint4((unsigned)s, *(unsigned*)&p01,
                                      *(unsigned*)&p23, *(unsigned*)&p4x);
                slots[(size_t)d * MAXD + pos] = pk;
            }
        }
        return;
    }

    // ---- projection part
    int pb = b / 3;                        // 0..1562
    int t  = threadIdx.x;
    int cg = t & 31;   // col group: cols 4cg..4cg+3
    int ng = t >> 5;   // node group 0..7 -> nodes n0..n0+3
    int n0 = pb * 32 + ng * 4;

    float4 alv = ((const float4*)attn_l)[cg];
    float4 arv = ((const float4*)attn_r)[cg];
    float al[4] = {alv.x, alv.y, alv.z, alv.w};
    float ar[4] = {arv.x, arv.y, arv.z, arv.w};

    float acc[4][4];
#pragma unroll
    for (int j = 0; j < 4; j++)
#pragma unroll
        for (int i = 0; i < 4; i++) acc[j][i] = 0.f;

    const float4* W4 = (const float4*)W_fc;    // [256][32] of float4
    const float4* F4 = (const float4*)feat;    // [N][64]  of float4

    for (int k4 = 0; k4 < IN_DIM / 4; ++k4) {
        int k = k4 * 4;
        float4 w0 = W4[(k + 0) * 32 + cg];
        float4 w1 = W4[(k + 1) * 32 + cg];
        float4 w2 = W4[(k + 2) * 32 + cg];
        float4 w3 = W4[(k + 3) * 32 + cg];
        float wr0[4] = {w0.x, w0.y, w0.z, w0.w};
        float wr1[4] = {w1.x, w1.y, w1.z, w1.w};
        float wr2[4] = {w2.x, w2.y, w2.z, w2.w};
        float wr3[4] = {w3.x, w3.y, w3.z, w3.w};
#pragma unroll
        for (int j = 0; j < 4; j++) {
            int n  = n0 + j;
            int na = n < N_NODES ? n : 0;
            float4 fu = F4[(size_t)na * 64 + k4];
#pragma unroll
            for (int i = 0; i < 4; i++)
                acc[j][i] += fu.x * wr0[i] + fu.y * wr1[i] + fu.z * wr2[i] + fu.w * wr3[i];
        }
    }

#pragma unroll
    for (int j = 0; j < 4; j++) {
        int n = n0 + j;
        float pl = acc[j][0]*al[0] + acc[j][1]*al[1] + acc[j][2]*al[2] + acc[j][3]*al[3];
        float pr = acc[j][0]*ar[0] + acc[j][1]*ar[1] + acc[j][2]*ar[2] + acc[j][3]*ar[3];
        pl += __shfl_down(pl, 4, 8); pl += __shfl_down(pl, 2, 8); pl += __shfl_down(pl, 1, 8);
        pr += __shfl_down(pr, 4, 8); pr += __shfl_down(pr, 2, 8); pr += __shfl_down(pr, 1, 8);
        if (n < N_NODES) {
            if ((cg & 7) == 0) {
                int h = cg >> 3;
                el[n * H_HEADS + h] = pl;
                er[n * H_HEADS + h] = pr;
            }
            __half2 p0 = __floats2half2_rn(acc[j][0], acc[j][1]);
            __half2 p1 = __floats2half2_rn(acc[j][2], acc[j][3]);
            uint2 pk = make_uint2(*(unsigned*)&p0, *(unsigned*)&p1);
            ((uint2*)(feat_src + (size_t)n * 64))[cg] = pk;
        }
    }
}

__device__ __forceinline__ void acc8f(float* acc, uint4 v, float a) {
    float2 f;
    f = __half22float2(*(__half2*)&v.x); acc[0] += a * f.x; acc[1] += a * f.y;
    f = __half22float2(*(__half2*)&v.y); acc[2] += a * f.x; acc[3] += a * f.y;
    f = __half22float2(*(__half2*)&v.z); acc[4] += a * f.x; acc[5] += a * f.y;
    f = __half22float2(*(__half2*)&v.w); acc[6] += a * f.x; acc[7] += a * f.y;
}

// ---------------- K2: quarter-wave-per-node gather (payload slots, no random edge reads)
__global__ __launch_bounds__(256) void k_gather_out(
    const int* __restrict__ cnt, const uint4* __restrict__ slots,
    const float* __restrict__ el, const float* __restrict__ er,
    const __half2* __restrict__ feat_src,   // [N,64] half2
    const float* __restrict__ W_edg, const float* __restrict__ b_edg,
    const float* __restrict__ attn_edg,
    const float* __restrict__ W_out, const float* __restrict__ b_out,
    const float* __restrict__ bias,
    float* __restrict__ out)      // [N,128] f32
{
    __shared__ float sWe[100], sBe[20], sA[20], sWo[37 * 32], sBo[32], sBi[128];
    __shared__ __half2 sav2[NPB * 130];   // per node: {a0a1, a2a3} per edge, row stride 130
    __shared__ int   ssrc[NPB * 66];      // per node: src ids, row pad 66
    __shared__ float sft[NPB * 132];      // per node: ft[128], row pad 132
    int t = threadIdx.x;
    if (t < 100) sWe[t] = W_edg[t];
    if (t < 20) { sBe[t] = b_edg[t]; sA[t] = attn_edg[t]; }
    for (int i = t; i < 37 * 32; i += 256) sWo[i] = W_out[i];
    if (t < 32)  sBo[t] = b_out[t];
    if (t < 128) sBi[t] = bias[t];
    __syncthreads();

    int lane = t & 63;
    int wv   = t >> 6;
    int q    = lane >> 4;      // quarter 0..3
    int ql   = lane & 15;      // lane in quarter
    int nb   = wv * 4 + q;     // node-in-block 0..15
    int n    = blockIdx.x * NPB + nb;   // grid exact: 3125*16 = 50000
    int h    = ql >> 2;        // head of this lane's 8 channels

    int dq = cnt[n]; if (dq > MAXD) dq = MAXD;

    // defensive init so clamped/empty reads form safe addresses
    if (ql == 0) ssrc[nb * 66] = 0;

    float4 ern = ((const float4*)er)[n];

    // attention collapse: ee[h] = cst[h] + sum_i ef[i]*WA[i][h]
    float WA[5][4], cst[4];
#pragma unroll
    for (int hh = 0; hh < 4; hh++) {
        float c0 = 0.f;
#pragma unroll
        for (int dd = 0; dd < 5; dd++) c0 += sBe[hh * 5 + dd] * sA[hh * 5 + dd];
        cst[hh] = c0;
#pragma unroll
        for (int i = 0; i < 5; i++) {
            float w = 0.f;
#pragma unroll
            for (int dd = 0; dd < 5; dd++) w += sWe[i * 20 + hh * 5 + dd] * sA[hh * 5 + dd];
            WA[i][hh] = w;
        }
    }

    // wave-max degree
    int dmax = dq;
    { int o = __shfl_xor(dmax, 16); dmax = dmax > o ? dmax : o;
      o = __shfl_xor(dmax, 32);     dmax = dmax > o ? dmax : o; }

    float sa4[4] = {0.f, 0.f, 0.f, 0.f};
    float m[20];
#pragma unroll
    for (int i = 0; i < 20; i++) m[i] = 0.f;

    // ---- phase 1: coalesced payload read + el gather; logits+exp; meta -> LDS
    for (int r = 0; r < dmax; r += 16) {
        int idx = r + ql;
        if (idx < dq) {
            uint4 pay = slots[(size_t)n * MAXD + idx];
            int s = (int)pay.x;
            float2 e01 = __half22float2(*(__half2*)&pay.y);
            float2 e23 = __half22float2(*(__half2*)&pay.z);
            float2 e4x = __half22float2(*(__half2*)&pay.w);
            float ef0 = e01.x, ef1 = e01.y, ef2 = e23.x, ef3 = e23.y, ef4 = e4x.x;
            float4 els = ((const float4*)el)[s];
            float lv0 = els.x + ern.x + cst[0] + ef0*WA[0][0] + ef1*WA[1][0] + ef2*WA[2][0] + ef3*WA[3][0] + ef4*WA[4][0];
            float lv1 = els.y + ern.y + cst[1] + ef0*WA[0][1] + ef1*WA[1][1] + ef2*WA[2][1] + ef3*WA[3][1] + ef4*WA[4][1];
            float lv2 = els.z + ern.z + cst[2] + ef0*WA[0][2] + ef1*WA[1][2] + ef2*WA[2][2] + ef3*WA[3][2] + ef4*WA[4][2];
            float lv3 = els.w + ern.w + cst[3] + ef0*WA[0][3] + ef1*WA[1][3] + ef2*WA[2][3] + ef3*WA[3][3] + ef4*WA[4][3];
            lv0 = lv0 >= 0.f ? lv0 : NEG_SLOPE * lv0;
            lv1 = lv1 >= 0.f ? lv1 : NEG_SLOPE * lv1;
            lv2 = lv2 >= 0.f ? lv2 : NEG_SLOPE * lv2;
            lv3 = lv3 >= 0.f ? lv3 : NEG_SLOPE * lv3;
            float a0 = __expf(lv0), a1 = __expf(lv1), a2 = __expf(lv2), a3 = __expf(lv3);
            sa4[0] += a0; sa4[1] += a1; sa4[2] += a2; sa4[3] += a3;
            m[0]  += a0 * ef0; m[1]  += a0 * ef1; m[2]  += a0 * ef2; m[3]  += a0 * ef3; m[4]  += a0 * ef4;
            m[5]  += a1 * ef0; m[6]  += a1 * ef1; m[7]  += a1 * ef2; m[8]  += a1 * ef3; m[9]  += a1 * ef4;
            m[10] += a2 * ef0; m[11] += a2 * ef1; m[12] += a2 * ef2; m[13] += a2 * ef3; m[14] += a2 * ef4;
            m[15] += a3 * ef0; m[16] += a3 * ef1; m[17] += a3 * ef2; m[18] += a3 * ef3; m[19] += a3 * ef4;
            ssrc[nb * 66 + idx] = s;
            sav2[nb * 130 + idx * 2]     = __floats2half2_rn(a0, a1);
            sav2[nb * 130 + idx * 2 + 1] = __floats2half2_rn(a2, a3);
        }
    }

    // ---- phase 2: gather feat_src rows; 1 dwordx4 instr serves 4 edges (4 quarters)
    float acc[8];
#pragma unroll
    for (int k = 0; k < 8; k++) acc[k] = 0.f;
    const uint4* fs4 = (const uint4*)feat_src;   // row = 16 uint4
    int hp  = h >> 1;      // which half2 holds my head's a
    int hc  = h & 1;
    int sab = nb * 130;
    int sib = nb * 66;

    for (int j = 0; j < dmax; j += 4) {
        int c0 = (j     < dq) ? j     : 0;
        int c1 = (j + 1 < dq) ? j + 1 : 0;
        int c2 = (j + 2 < dq) ? j + 2 : 0;
        int c3 = (j + 3 < dq) ? j + 3 : 0;
        float2 f0 = __half22float2(sav2[sab + c0 * 2 + hp]);
        float2 f1 = __half22float2(sav2[sab + c1 * 2 + hp]);
        float2 f2 = __half22float2(sav2[sab + c2 * 2 + hp]);
        float2 f3 = __half22float2(sav2[sab + c3 * 2 + hp]);
        float a0 = (j     < dq) ? (hc ? f0.y : f0.x) : 0.f;
        float a1 = (j + 1 < dq) ? (hc ? f1.y : f1.x) : 0.f;
        float a2 = (j + 2 < dq) ? (hc ? f2.y : f2.x) : 0.f;
        float a3 = (j + 3 < dq) ? (hc ? f3.y : f3.x) : 0.f;
        int s0 = ssrc[sib + c0];
        int s1 = ssrc[sib + c1];
        int s2 = ssrc[sib + c2];
        int s3 = ssrc[sib + c3];
        uint4 v0 = fs4[(size_t)s0 * 16 + ql];
        uint4 v1 = fs4[(size_t)s1 * 16 + ql];
        uint4 v2 = fs4[(size_t)s2 * 16 + ql];
        uint4 v3 = fs4[(size_t)s3 * 16 + ql];
        acc8f(acc, v0, a0);
        acc8f(acc, v1, a1);
        acc8f(acc, v2, a2);
        acc8f(acc, v3, a3);
    }

    // ---- quarter reduction (16 lanes): denoms + moments
#pragma unroll
    for (int off = 1; off < 16; off <<= 1) {
#pragma unroll
        for (int hh = 0; hh < 4; hh++) sa4[hh] += __shfl_xor(sa4[hh], off);
#pragma unroll
        for (int qq = 0; qq < 20; qq++) m[qq] += __shfl_xor(m[qq], off);
    }
    float rh = sa4[h] > 0.f ? 1.f / sa4[h] : 0.f;
#pragma unroll
    for (int k = 0; k < 8; k++) acc[k] *= rh;

    // ft transpose (wave-internal LDS, no barrier needed)
    *(float4*)&sft[nb * 132 + 8 * ql]     = make_float4(acc[0], acc[1], acc[2], acc[3]);
    *(float4*)&sft[nb * 132 + 8 * ql + 4] = make_float4(acc[4], acc[5], acc[6], acc[7]);

    // ft_f for this head from reduced moments (0 if no edges, matching segment_sum)
    float ftf[5];
#pragma unroll
    for (int d = 0; d < 5; d++) {
        float s = 0.f;
#pragma unroll
        for (int i = 0; i < 5; i++) s += m[h * 5 + i] * sWe[i * 20 + h * 5 + d];
        ftf[d] = (dq > 0) ? (sBe[h * 5 + d] + s * rh) : 0.f;
    }

    // ---- output: lane covers channels cc = 8ql..8ql+7 (head h, f = 8*(ql&3)+k)
    int f0 = 8 * (ql & 3);
    float o[8];
#pragma unroll
    for (int k = 0; k < 8; k++) {
        int f = f0 + k, cc = h * 32 + f;
        o[k] = sBo[f] + sBi[cc];
#pragma unroll
        for (int d = 0; d < 5; d++) o[k] += ftf[d] * sWo[d * 32 + f];
    }
    for (int g = 0; g < 32; g++) {
        float ftg = sft[nb * 132 + h * 32 + g];
#pragma unroll
        for (int k = 0; k < 8; k++) o[k] += ftg * sWo[(5 + g) * 32 + f0 + k];
    }
    float4* po = (float4*)(out + (size_t)n * HF + 8 * ql);
    po[0] = make_float4(o[0], o[1], o[2], o[3]);
    po[1] = make_float4(o[4], o[5], o[6], o[7]);
}

extern "C" void kernel_launch(void* const* d_in, const int* in_sizes, int n_in,
                              void* d_out, int out_size, void* d_ws, size_t ws_size,
                              hipStream_t stream) {
    const float* feat     = (const float*)d_in[0];
    const float* edge_fea = (const float*)d_in[1];
    const int*   src      = (const int*)d_in[2];
    const int*   dst      = (const int*)d_in[3];
    const float* W_fc     = (const float*)d_in[4];
    const float* W_edg    = (const float*)d_in[5];
    const float* b_edg    = (const float*)d_in[6];
    const float* attn_l   = (const float*)d_in[7];
    const float* attn_r   = (const float*)d_in[8];
    const float* attn_edg = (const float*)d_in[9];
    const float* W_out    = (const float*)d_in[10];
    const float* b_out    = (const float*)d_in[11];
    const float* bias     = (const float*)d_in[12];

    float* ws         = (float*)d_ws;
    __half2* feat_src = (__half2*)ws;                            // N*64 half2 (12.8 MB)
    float* el         = ws + (size_t)N_NODES * 64;               // N*4 f32
    float* er         = el + N_NODES * H_HEADS;                  // N*4 f32
    int*   cnt        = (int*)(er + N_NODES * H_HEADS);          // N int
    uint4* slots      = (uint4*)(cnt + N_NODES);                 // N*MAXD*16B (51.2 MB)
    // total ~66 MB

    hipMemsetAsync(cnt, 0, (size_t)N_NODES * sizeof(int), stream);

    k_proj_scatter<<<TOT_BLOCKS, 256, 0, stream>>>(
        feat, W_fc, attn_l, attn_r, src, dst, edge_fea,
        feat_src, el, er, cnt, slots);
    k_gather_out<<<N_NODES / NPB, 256, 0, stream>>>(
        cnt, slots, el, er, feat_src,
        W_edg, b_edg, attn_edg, W_out, b_out, bias, (float*)d_out);
}